// Round 1
// baseline (471.802 us; speedup 1.0000x reference)
//
#include <hip/hip_runtime.h>
#include <math.h>

#define BATCH 32
#define HH 512
#define WW 512
#define TW 64
#define TH 16
#define HALO 2
#define SW (TW + 2*HALO)   // 68
#define SH (TH + 2*HALO)   // 20
#define NTILEX (WW / TW)   // 8
#define NTILEY (HH / TH)   // 32
#define NPIX ((float)BATCH * HH * WW)

// ws layout (floats): [0]=ce_sum [1]=valid_cnt [2]=focal_sum
// [3+3b+0]=inter_b [3+3b+1]=sum_bp_b [3+3b+2]=sum_bt_b   (b in 0..31)  => 99 floats
#define WS_FLOATS 99

__global__ void zero_ws_kernel(float* ws) {
    int i = threadIdx.x;
    if (i < WS_FLOATS) ws[i] = 0.0f;
}

__global__ __launch_bounds__(256) void bel_main_kernel(
        const float* __restrict__ pred,
        const int*   __restrict__ target,
        float*       __restrict__ ws) {
    __shared__ int   stgt[SH][SW];     // target tile + halo
    __shared__ int   hsum[SH][TW];     // horizontal 5-sums
    __shared__ float red[6][4];

    const int tid = threadIdx.x;
    const int bid = blockIdx.x;
    const int bx = bid % NTILEX;
    const int by = (bid / NTILEX) % NTILEY;
    const int b  = bid / (NTILEX * NTILEY);

    const int gx0 = bx * TW - HALO;
    const int gy0 = by * TH - HALO;
    const int tb  = b * HH * WW;       // target base; pred base = 2*tb

    // ---- stage target tile (+halo) with zero padding (SAME conv) ----
    for (int i = tid; i < SH * SW; i += 256) {
        int r = i / SW, c = i - r * SW;
        int gy = gy0 + r, gx = gx0 + c;
        int v = 0;
        if ((unsigned)gy < (unsigned)HH && (unsigned)gx < (unsigned)WW)
            v = target[tb + gy * WW + gx];
        stgt[r][c] = v;
    }
    __syncthreads();

    // ---- horizontal 5-sum ----
    for (int i = tid; i < SH * TW; i += 256) {
        int r = i >> 6, c = i & 63;
        hsum[r][c] = stgt[r][c] + stgt[r][c+1] + stgt[r][c+2]
                   + stgt[r][c+3] + stgt[r][c+4];
    }
    __syncthreads();

    const int tx = tid & 63;
    const int ty = tid >> 6;   // 0..3

    float ce_acc = 0.f, cnt_acc = 0.f, focal_acc = 0.f;
    float inter_acc = 0.f, bp_acc = 0.f, bt_acc = 0.f;

    #pragma unroll
    for (int k = 0; k < TH / 4; ++k) {
        const int yl = ty + 4 * k;
        const int y  = by * TH + yl;
        const int x  = bx * TW + tx;

        // vertical 5-sum of horizontal sums -> 5x5 box sum
        const int s = hsum[yl][tx] + hsum[yl+1][tx] + hsum[yl+2][tx]
                    + hsum[yl+3][tx] + hsum[yl+4][tx];
        // boundary = (s>0) - (s>24)  in {0,1}
        const float bm = (s > 0 && s <= 24) ? 1.0f : 0.0f;

        const int t = stgt[yl + HALO][tx + HALO];

        const int pix = y * WW + x;
        const float p0 = pred[2*tb + pix];
        const float p1 = pred[2*tb + HH*WW + pix];

        // stable 2-class logsumexp
        const float m   = fmaxf(p0, p1);
        const float d   = fabsf(p0 - p1);
        const float lse = m + __logf(1.0f + __expf(-d));

        const int   tc = (t < 0) ? 0 : ((t > 1) ? 1 : t);  // clip like take_along_axis
        const float pt_logit = tc ? p1 : p0;
        const float ce = lse - pt_logit;                    // per-pixel CE

        const float valid = (t != 250) ? 1.0f : 0.0f;
        ce_acc  += ce * valid;
        cnt_acc += valid;

        const float pt  = __expf(-ce);
        const float omp = 1.0f - pt;
        focal_acc += 0.25f * omp * omp * ce;                // FOCAL_ALPHA=0.25, GAMMA=2

        const float prob1 = __expf(p1 - lse);
        const float bp = prob1 * bm;
        const float bt = (float)t * bm;
        inter_acc += bp * bt;
        bp_acc    += bp;
        bt_acc    += bt;
    }

    // ---- block reduction: wave shuffle then across 4 waves ----
    float vals[6] = {ce_acc, cnt_acc, focal_acc, inter_acc, bp_acc, bt_acc};
    #pragma unroll
    for (int j = 0; j < 6; ++j) {
        float v = vals[j];
        #pragma unroll
        for (int off = 32; off > 0; off >>= 1)
            v += __shfl_down(v, off, 64);
        vals[j] = v;
    }
    const int wave = tid >> 6;
    const int lane = tid & 63;
    if (lane == 0) {
        #pragma unroll
        for (int j = 0; j < 6; ++j) red[j][wave] = vals[j];
    }
    __syncthreads();
    if (tid == 0) {
        #pragma unroll
        for (int j = 0; j < 6; ++j)
            vals[j] = red[j][0] + red[j][1] + red[j][2] + red[j][3];
        atomicAdd(&ws[0], vals[0]);
        atomicAdd(&ws[1], vals[1]);
        atomicAdd(&ws[2], vals[2]);
        atomicAdd(&ws[3 + 3*b + 0], vals[3]);
        atomicAdd(&ws[3 + 3*b + 1], vals[4]);
        atomicAdd(&ws[3 + 3*b + 2], vals[5]);
    }
}

__global__ void bel_finalize_kernel(const float* __restrict__ ws,
                                    float* __restrict__ out) {
    if (threadIdx.x == 0) {
        const float ce_sum    = ws[0];
        const float cnt       = ws[1];
        const float focal_sum = ws[2];
        const float ce_loss = ce_sum / fmaxf(cnt, 1.0f);
        const float focal   = focal_sum / NPIX;
        float dsum = 0.0f;
        for (int b = 0; b < BATCH; ++b) {
            const float inter = ws[3 + 3*b + 0];
            const float uni   = ws[3 + 3*b + 1] + ws[3 + 3*b + 2];
            dsum += 2.0f * inter / (uni + 1e-8f);
        }
        const float bdice = 1.0f - dsum / (float)BATCH;
        out[0] = ce_loss + focal + bdice;   // BOUNDARY_W = 1.0
    }
}

extern "C" void kernel_launch(void* const* d_in, const int* in_sizes, int n_in,
                              void* d_out, int out_size, void* d_ws, size_t ws_size,
                              hipStream_t stream) {
    const float* pred   = (const float*)d_in[0];
    const int*   target = (const int*)d_in[1];
    float* ws  = (float*)d_ws;
    float* out = (float*)d_out;

    zero_ws_kernel<<<1, 128, 0, stream>>>(ws);
    bel_main_kernel<<<NTILEX * NTILEY * BATCH, 256, 0, stream>>>(pred, target, ws);
    bel_finalize_kernel<<<1, 64, 0, stream>>>(ws, out);
}

// Round 2
// 134.467 us; speedup vs baseline: 3.5087x; 3.5087x over previous
//
#include <hip/hip_runtime.h>
#include <math.h>

#define BATCH 32
#define HH 512
#define WW 512
#define TW 64
#define TH 16
#define HALO 2
#define SW (TW + 2*HALO)   // 68
#define SH (TH + 2*HALO)   // 20
#define NTILEX (WW / TW)   // 8
#define NTILEY (HH / TH)   // 32
#define NPIX ((float)BATCH * HH * WW)

// ws layout: 6 quantities x 32 images, each accumulator padded to its own
// 128B L2 line (32 floats) to avoid same-line atomic serialization.
// slot(j,b) j in 0..5: 0=ce 1=valid_cnt 2=focal 3=inter 4=sum_bp 5=sum_bt
#define SLOT(j,b) ((((j) * BATCH) + (b)) * 32)
#define WS_FLOATS (6 * BATCH * 32)   // 6144 floats = 24 KB

__global__ void zero_ws_kernel(float* ws) {
    int i = blockIdx.x * 256 + threadIdx.x;
    if (i < WS_FLOATS) ws[i] = 0.0f;
}

__global__ __launch_bounds__(256) void bel_main_kernel(
        const float* __restrict__ pred,
        const int*   __restrict__ target,
        float*       __restrict__ ws) {
    __shared__ int   stgt[SH][SW];     // target tile + halo
    __shared__ int   hsum[SH][TW];     // horizontal 5-sums
    __shared__ float red[6][4];

    const int tid = threadIdx.x;
    const int bid = blockIdx.x;
    const int bx = bid % NTILEX;
    const int by = (bid / NTILEX) % NTILEY;
    const int b  = bid / (NTILEX * NTILEY);

    const int gx0 = bx * TW - HALO;
    const int gy0 = by * TH - HALO;
    const int tb  = b * HH * WW;       // target base; pred base = 2*tb

    // ---- stage target tile (+halo) with zero padding (SAME conv) ----
    for (int i = tid; i < SH * SW; i += 256) {
        int r = i / SW, c = i - r * SW;
        int gy = gy0 + r, gx = gx0 + c;
        int v = 0;
        if ((unsigned)gy < (unsigned)HH && (unsigned)gx < (unsigned)WW)
            v = target[tb + gy * WW + gx];
        stgt[r][c] = v;
    }
    __syncthreads();

    // ---- horizontal 5-sum ----
    for (int i = tid; i < SH * TW; i += 256) {
        int r = i >> 6, c = i & 63;
        hsum[r][c] = stgt[r][c] + stgt[r][c+1] + stgt[r][c+2]
                   + stgt[r][c+3] + stgt[r][c+4];
    }
    __syncthreads();

    const int tx = tid & 63;
    const int ty = tid >> 6;   // 0..3

    float ce_acc = 0.f, cnt_acc = 0.f, focal_acc = 0.f;
    float inter_acc = 0.f, bp_acc = 0.f, bt_acc = 0.f;

    #pragma unroll
    for (int k = 0; k < TH / 4; ++k) {
        const int yl = ty + 4 * k;
        const int y  = by * TH + yl;
        const int x  = bx * TW + tx;

        // vertical 5-sum of horizontal sums -> 5x5 box sum
        const int s = hsum[yl][tx] + hsum[yl+1][tx] + hsum[yl+2][tx]
                    + hsum[yl+3][tx] + hsum[yl+4][tx];
        // boundary = (s>0) - (s>24)  in {0,1}
        const float bm = (s > 0 && s <= 24) ? 1.0f : 0.0f;

        const int t = stgt[yl + HALO][tx + HALO];

        const int pix = y * WW + x;
        const float p0 = pred[2*tb + pix];
        const float p1 = pred[2*tb + HH*WW + pix];

        // stable 2-class logsumexp
        const float m   = fmaxf(p0, p1);
        const float d   = fabsf(p0 - p1);
        const float lse = m + __logf(1.0f + __expf(-d));

        const int   tc = (t < 0) ? 0 : ((t > 1) ? 1 : t);  // clip like take_along_axis
        const float pt_logit = tc ? p1 : p0;
        const float ce = lse - pt_logit;                    // per-pixel CE

        const float valid = (t != 250) ? 1.0f : 0.0f;
        ce_acc  += ce * valid;
        cnt_acc += valid;

        const float pt  = __expf(-ce);
        const float omp = 1.0f - pt;
        focal_acc += 0.25f * omp * omp * ce;                // FOCAL_ALPHA=0.25, GAMMA=2

        const float prob1 = __expf(p1 - lse);
        const float bp = prob1 * bm;
        const float bt = (float)t * bm;
        inter_acc += bp * bt;
        bp_acc    += bp;
        bt_acc    += bt;
    }

    // ---- block reduction: wave shuffle then across 4 waves ----
    float vals[6] = {ce_acc, cnt_acc, focal_acc, inter_acc, bp_acc, bt_acc};
    #pragma unroll
    for (int j = 0; j < 6; ++j) {
        float v = vals[j];
        #pragma unroll
        for (int off = 32; off > 0; off >>= 1)
            v += __shfl_down(v, off, 64);
        vals[j] = v;
    }
    const int wave = tid >> 6;
    const int lane = tid & 63;
    if (lane == 0) {
        #pragma unroll
        for (int j = 0; j < 6; ++j) red[j][wave] = vals[j];
    }
    __syncthreads();
    if (tid == 0) {
        #pragma unroll
        for (int j = 0; j < 6; ++j) {
            vals[j] = red[j][0] + red[j][1] + red[j][2] + red[j][3];
            // per-image accumulator, own cache line: 256 blocks/address max
            atomicAdd(&ws[SLOT(j, b)], vals[j]);
        }
    }
}

__global__ void bel_finalize_kernel(const float* __restrict__ ws,
                                    float* __restrict__ out) {
    const int t = threadIdx.x;   // one wave of 64
    float ce_p = 0.f, cnt_p = 0.f, focal_p = 0.f, dice_p = 0.f;
    if (t < BATCH) {
        ce_p    = ws[SLOT(0, t)];
        cnt_p   = ws[SLOT(1, t)];
        focal_p = ws[SLOT(2, t)];
        const float inter = ws[SLOT(3, t)];
        const float uni   = ws[SLOT(4, t)] + ws[SLOT(5, t)];
        dice_p = 2.0f * inter / (uni + 1e-8f);
    }
    #pragma unroll
    for (int off = 32; off > 0; off >>= 1) {
        ce_p    += __shfl_down(ce_p, off, 64);
        cnt_p   += __shfl_down(cnt_p, off, 64);
        focal_p += __shfl_down(focal_p, off, 64);
        dice_p  += __shfl_down(dice_p, off, 64);
    }
    if (t == 0) {
        const float ce_loss = ce_p / fmaxf(cnt_p, 1.0f);
        const float focal   = focal_p / NPIX;
        const float bdice   = 1.0f - dice_p / (float)BATCH;
        out[0] = ce_loss + focal + bdice;   // BOUNDARY_W = 1.0
    }
}

extern "C" void kernel_launch(void* const* d_in, const int* in_sizes, int n_in,
                              void* d_out, int out_size, void* d_ws, size_t ws_size,
                              hipStream_t stream) {
    const float* pred   = (const float*)d_in[0];
    const int*   target = (const int*)d_in[1];
    float* ws  = (float*)d_ws;
    float* out = (float*)d_out;

    zero_ws_kernel<<<(WS_FLOATS + 255) / 256, 256, 0, stream>>>(ws);
    bel_main_kernel<<<NTILEX * NTILEY * BATCH, 256, 0, stream>>>(pred, target, ws);
    bel_finalize_kernel<<<1, 64, 0, stream>>>(ws, out);
}

// Round 3
// 118.689 us; speedup vs baseline: 3.9751x; 1.1329x over previous
//
#include <hip/hip_runtime.h>
#include <math.h>

#define BATCH 32
#define HH 512
#define WW 512
#define TH 16                  // output rows per block
#define HALO 2
#define SRH (TH + 2*HALO)      // 20 staged rows
#define NDW (WW / 4)           // 128 dwords per row (u8-packed)
#define CSTRIDE 132            // csum row stride in dwords (1 pad + 128 + 1 pad + 2 slack)
#define NPIX ((float)BATCH * HH * WW)
#define HW (HH * WW)

// ws layout: 6 quantities x 32 images, each on its own 128B line.
// j: 0=ce 1=valid_cnt 2=focal 3=inter 4=sum_bp 5=sum_bt
#define SLOT(j,b) ((((j) * BATCH) + (b)) * 32)
#define WS_FLOATS (6 * BATCH * 32)

__global__ void zero_ws_kernel(float* ws) {
    int i = blockIdx.x * 256 + threadIdx.x;
    if (i < WS_FLOATS) ws[i] = 0.0f;
}

__global__ __launch_bounds__(256) void bel_main_kernel(
        const float* __restrict__ pred,
        const int*   __restrict__ target,
        float*       __restrict__ ws) {
    __shared__ unsigned int t8[SRH][NDW];      // target, 1 byte/pixel, 4/dword
    __shared__ unsigned int csum[TH][CSTRIDE]; // vertical 5-sums, packed u8
    __shared__ float red[6][4];

    const int tid = threadIdx.x;
    const int bid = blockIdx.x;
    const int b   = bid >> 5;          // image
    const int ty  = bid & 31;          // row-tile
    const int y0  = ty * TH;
    const size_t tb = (size_t)b * HW;

    // zero the horizontal pad dwords of csum (left=0, right=129)
    if (tid < 2 * TH) {
        int rr = tid >> 1;
        csum[rr][(tid & 1) ? (NDW + 1) : 0] = 0u;
    }

    // ---- stage 20 rows of target as packed u8 (zero rows outside image) ----
    #pragma unroll
    for (int it = 0; it < (SRH * NDW) / 256; ++it) {   // 10 iters
        const int i  = tid + 256 * it;
        const int r  = i >> 7;
        const int c4 = i & 127;
        const int gy = y0 - HALO + r;
        unsigned int packed = 0u;
        if ((unsigned)gy < (unsigned)HH) {
            const int4 v = *(const int4*)(target + tb + ((size_t)gy << 9) + (c4 << 2));
            packed = (unsigned)v.x | ((unsigned)v.y << 8)
                   | ((unsigned)v.z << 16) | ((unsigned)v.w << 24);
        }
        t8[r][c4] = packed;
    }
    __syncthreads();

    // ---- vertical 5-sum (packed u8 adds; max byte value 5, no carry) ----
    #pragma unroll
    for (int it = 0; it < (TH * NDW) / 256; ++it) {    // 8 iters
        const int j = tid + 256 * it;
        const int r = j >> 7;
        const int c = j & 127;
        csum[r][c + 1] = t8[r][c] + t8[r+1][c] + t8[r+2][c]
                       + t8[r+3][c] + t8[r+4][c];
    }
    __syncthreads();

    const float4* __restrict__ pr0 = (const float4*)(pred + tb * 2);
    const float4* __restrict__ pr1 = (const float4*)(pred + tb * 2 + HW);

    float ce_acc = 0.f, cnt_acc = 0.f, focal_acc = 0.f;
    float inter_acc = 0.f, bp_acc = 0.f, bt_acc = 0.f;

    const unsigned long long M5 = 0xFFFFFFFFFFull;      // 5 bytes
    const unsigned long long ALL5 = 0x0505050505ull;    // box sum == 25

    for (int it = 0; it < (TH * NDW) / 256; ++it) {     // 8 iters, 4 px each
        const int j = tid + 256 * it;
        const int r = j >> 7;
        const int g = j & 127;
        const int y = y0 + r;
        const int fidx = (y << 7) + g;                  // float4 index

        const float4 f0 = pr0[fidx];
        const float4 f1 = pr1[fidx];

        const unsigned int L = csum[r][g];
        const unsigned int M = csum[r][g + 1];
        const unsigned int R = csum[r][g + 2];
        const unsigned int tdw = t8[r + HALO][g];

        const unsigned long long lo  = (unsigned long long)L | ((unsigned long long)M << 32);
        const unsigned long long mid = (unsigned long long)M | ((unsigned long long)R << 32);

        #pragma unroll
        for (int i = 0; i < 4; ++i) {
            unsigned long long w;
            if      (i == 0) w = (lo  >> 16) & M5;
            else if (i == 1) w = (lo  >> 24) & M5;
            else if (i == 2) w =  mid        & M5;
            else             w = (mid >>  8) & M5;
            const float bm = (w != 0ull && w != ALL5) ? 1.0f : 0.0f;

            const unsigned int tv = (tdw >> (8 * i)) & 0xFFu;

            const float p0 = (i == 0) ? f0.x : (i == 1) ? f0.y : (i == 2) ? f0.z : f0.w;
            const float p1 = (i == 0) ? f1.x : (i == 1) ? f1.y : (i == 2) ? f1.z : f1.w;

            const float d  = p1 - p0;
            const float e  = __expf(-fabsf(d));
            const float rz = 1.0f / (1.0f + e);
            const float pmin = e * rz;
            const float prob1 = (d >= 0.0f) ? rz : pmin;
            const float pt = tv ? prob1 : (1.0f - prob1);
            const float ce = -__logf(pt);

            const float valid = (tv != 250u) ? 1.0f : 0.0f;
            ce_acc  += ce * valid;
            cnt_acc += valid;

            const float omp = 1.0f - pt;
            focal_acc += omp * omp * ce;                // *0.25 folded at the end

            const float bp = prob1 * bm;
            const float bt = (float)tv * bm;
            inter_acc += bp * bt;
            bp_acc    += bp;
            bt_acc    += bt;
        }
    }

    // ---- block reduction ----
    float vals[6] = {ce_acc, cnt_acc, focal_acc * 0.25f, inter_acc, bp_acc, bt_acc};
    #pragma unroll
    for (int jj = 0; jj < 6; ++jj) {
        float v = vals[jj];
        #pragma unroll
        for (int off = 32; off > 0; off >>= 1)
            v += __shfl_down(v, off, 64);
        vals[jj] = v;
    }
    const int wave = tid >> 6;
    const int lane = tid & 63;
    if (lane == 0) {
        #pragma unroll
        for (int jj = 0; jj < 6; ++jj) red[jj][wave] = vals[jj];
    }
    __syncthreads();
    if (tid == 0) {
        #pragma unroll
        for (int jj = 0; jj < 6; ++jj) {
            const float v = red[jj][0] + red[jj][1] + red[jj][2] + red[jj][3];
            atomicAdd(&ws[SLOT(jj, b)], v);
        }
    }
}

__global__ void bel_finalize_kernel(const float* __restrict__ ws,
                                    float* __restrict__ out) {
    const int t = threadIdx.x;   // one wave
    float ce_p = 0.f, cnt_p = 0.f, focal_p = 0.f, dice_p = 0.f;
    if (t < BATCH) {
        ce_p    = ws[SLOT(0, t)];
        cnt_p   = ws[SLOT(1, t)];
        focal_p = ws[SLOT(2, t)];
        const float inter = ws[SLOT(3, t)];
        const float uni   = ws[SLOT(4, t)] + ws[SLOT(5, t)];
        dice_p = 2.0f * inter / (uni + 1e-8f);
    }
    #pragma unroll
    for (int off = 32; off > 0; off >>= 1) {
        ce_p    += __shfl_down(ce_p, off, 64);
        cnt_p   += __shfl_down(cnt_p, off, 64);
        focal_p += __shfl_down(focal_p, off, 64);
        dice_p  += __shfl_down(dice_p, off, 64);
    }
    if (t == 0) {
        const float ce_loss = ce_p / fmaxf(cnt_p, 1.0f);
        const float focal   = focal_p / NPIX;
        const float bdice   = 1.0f - dice_p / (float)BATCH;
        out[0] = ce_loss + focal + bdice;   // BOUNDARY_W = 1.0
    }
}

extern "C" void kernel_launch(void* const* d_in, const int* in_sizes, int n_in,
                              void* d_out, int out_size, void* d_ws, size_t ws_size,
                              hipStream_t stream) {
    const float* pred   = (const float*)d_in[0];
    const int*   target = (const int*)d_in[1];
    float* ws  = (float*)d_ws;
    float* out = (float*)d_out;

    zero_ws_kernel<<<(WS_FLOATS + 255) / 256, 256, 0, stream>>>(ws);
    bel_main_kernel<<<BATCH * (HH / TH), 256, 0, stream>>>(pred, target, ws);
    bel_finalize_kernel<<<1, 64, 0, stream>>>(ws, out);
}

// Round 4
// 116.730 us; speedup vs baseline: 4.0418x; 1.0168x over previous
//
#include <hip/hip_runtime.h>
#include <math.h>

#define BATCH 32
#define HH 512
#define WW 512
#define TH 16                  // output rows per block
#define HALO 2
#define SRH (TH + 2*HALO)      // 20 staged rows
#define NDW (WW / 4)           // 128 dwords per row (u8-packed)
#define CSTRIDE 132            // csum row stride in dwords (1 pad + 128 + 1 pad + 2 slack)
#define NPIX ((float)BATCH * HH * WW)
#define HW (HH * WW)
#define NBLK (BATCH * (HH / TH))   // 1024

// ws layout: 8 floats per block (6 used): [bid*8 + j]
// j: 0=ce 1=valid_cnt 2=focal 3=inter 4=sum_bp 5=sum_bt
// Non-atomic: every slot read by finalize is written every call (poison-safe).

__global__ __launch_bounds__(256, 4) void bel_main_kernel(
        const float* __restrict__ pred,
        const int*   __restrict__ target,
        float*       __restrict__ ws) {
    __shared__ unsigned int t8[SRH][NDW];      // target, 1 byte/pixel
    __shared__ unsigned int csum[TH][CSTRIDE]; // vertical 5-sums, packed u8
    __shared__ float red[6][4];

    const int tid = threadIdx.x;
    const int bid = blockIdx.x;
    const int b   = bid >> 5;          // image
    const int ty  = bid & 31;          // row-tile
    const int y0  = ty * TH;
    const size_t tb = (size_t)b * HW;

    // zero the horizontal pad dwords of csum (left=0, right=NDW+1)
    if (tid < 2 * TH) {
        int rr = tid >> 1;
        csum[rr][(tid & 1) ? (NDW + 1) : 0] = 0u;
    }

    // ---- stage 20 rows of target as packed u8 (zero rows outside image) ----
    #pragma unroll
    for (int it = 0; it < (SRH * NDW) / 256; ++it) {   // 10 iters
        const int i  = tid + 256 * it;
        const int r  = i >> 7;
        const int c4 = i & 127;
        const int gy = y0 - HALO + r;
        unsigned int packed = 0u;
        if ((unsigned)gy < (unsigned)HH) {
            const int4 v = *(const int4*)(target + tb + ((size_t)gy << 9) + (c4 << 2));
            packed = (unsigned)v.x | ((unsigned)v.y << 8)
                   | ((unsigned)v.z << 16) | ((unsigned)v.w << 24);
        }
        t8[r][c4] = packed;
    }
    __syncthreads();

    // ---- vertical 5-sum (packed u8 adds; max byte value 5, no carry) ----
    #pragma unroll
    for (int it = 0; it < (TH * NDW) / 256; ++it) {    // 8 iters
        const int j = tid + 256 * it;
        const int r = j >> 7;
        const int c = j & 127;
        csum[r][c + 1] = t8[r][c] + t8[r+1][c] + t8[r+2][c]
                       + t8[r+3][c] + t8[r+4][c];
    }
    __syncthreads();

    // ---- batched pred prefetch: 16 float4 loads in flight per thread ----
    const float4* __restrict__ pr0 = (const float4*)(pred + tb * 2);
    const float4* __restrict__ pr1 = (const float4*)(pred + tb * 2 + HW);
    const int base4 = (y0 << 7) + tid;   // float4 index of this thread's slot 0

    float4 F0[8], F1[8];
    #pragma unroll
    for (int it = 0; it < 8; ++it) F0[it] = pr0[base4 + 256 * it];
    #pragma unroll
    for (int it = 0; it < 8; ++it) F1[it] = pr1[base4 + 256 * it];

    float ce_acc = 0.f, cnt_acc = 0.f, focal_acc = 0.f;
    float inter_acc = 0.f, bp_acc = 0.f, bt_acc = 0.f;

    const unsigned long long M5 = 0xFFFFFFFFFFull;      // 5 bytes
    const unsigned long long ALL5 = 0x0505050505ull;    // box sum == 25

    const int g  = tid & 127;          // loop-invariant column group
    const int rb = tid >> 7;           // 0 or 1

    #pragma unroll
    for (int it = 0; it < 8; ++it) {
        const int r = rb + 2 * it;

        const float4 f0 = F0[it];
        const float4 f1 = F1[it];

        const unsigned int L = csum[r][g];
        const unsigned int M = csum[r][g + 1];
        const unsigned int R = csum[r][g + 2];
        const unsigned int tdw = t8[r + HALO][g];

        const unsigned long long lo  = (unsigned long long)L | ((unsigned long long)M << 32);
        const unsigned long long mid = (unsigned long long)M | ((unsigned long long)R << 32);

        #pragma unroll
        for (int i = 0; i < 4; ++i) {
            unsigned long long w;
            if      (i == 0) w = (lo  >> 16) & M5;
            else if (i == 1) w = (lo  >> 24) & M5;
            else if (i == 2) w =  mid        & M5;
            else             w = (mid >>  8) & M5;
            const float bm = (w != 0ull && w != ALL5) ? 1.0f : 0.0f;

            const unsigned int tv = (tdw >> (8 * i)) & 0xFFu;

            const float p0 = (i == 0) ? f0.x : (i == 1) ? f0.y : (i == 2) ? f0.z : f0.w;
            const float p1 = (i == 0) ? f1.x : (i == 1) ? f1.y : (i == 2) ? f1.z : f1.w;

            const float d  = p1 - p0;
            const float e  = __expf(-fabsf(d));
            const float rz = 1.0f / (1.0f + e);
            const float pmin = e * rz;
            const float prob1 = (d >= 0.0f) ? rz : pmin;
            const float pt = tv ? prob1 : (1.0f - prob1);
            const float ce = -__logf(pt);

            const float valid = (tv != 250u) ? 1.0f : 0.0f;
            ce_acc  += ce * valid;
            cnt_acc += valid;

            const float omp = 1.0f - pt;
            focal_acc += omp * omp * ce;                // *0.25 folded at the end

            const float bp = prob1 * bm;
            const float bt = (float)tv * bm;
            inter_acc += bp * bt;
            bp_acc    += bp;
            bt_acc    += bt;
        }
    }

    // ---- block reduction ----
    float vals[6] = {ce_acc, cnt_acc, focal_acc * 0.25f, inter_acc, bp_acc, bt_acc};
    #pragma unroll
    for (int jj = 0; jj < 6; ++jj) {
        float v = vals[jj];
        #pragma unroll
        for (int off = 32; off > 0; off >>= 1)
            v += __shfl_down(v, off, 64);
        vals[jj] = v;
    }
    const int wave = tid >> 6;
    const int lane = tid & 63;
    if (lane == 0) {
        #pragma unroll
        for (int jj = 0; jj < 6; ++jj) red[jj][wave] = vals[jj];
    }
    __syncthreads();
    if (tid == 0) {
        float* p = ws + bid * 8;
        #pragma unroll
        for (int jj = 0; jj < 6; ++jj)
            p[jj] = red[jj][0] + red[jj][1] + red[jj][2] + red[jj][3];
    }
}

__global__ void bel_finalize_kernel(const float* __restrict__ ws,
                                    float* __restrict__ out) {
    __shared__ float simg[BATCH][4];
    const int t = threadIdx.x;          // 256 threads
    const int b = t >> 3;               // image 0..31
    const int s = t & 7;                // 8 lanes per image

    float a0 = 0.f, a1 = 0.f, a2 = 0.f, a3 = 0.f, a4 = 0.f, a5 = 0.f;
    #pragma unroll
    for (int k = 0; k < 4; ++k) {
        const int bid = (b << 5) + s + (k << 3);
        const float* p = ws + bid * 8;
        a0 += p[0]; a1 += p[1]; a2 += p[2];
        a3 += p[3]; a4 += p[4]; a5 += p[5];
    }
    #pragma unroll
    for (int off = 4; off > 0; off >>= 1) {
        a0 += __shfl_down(a0, off, 8);
        a1 += __shfl_down(a1, off, 8);
        a2 += __shfl_down(a2, off, 8);
        a3 += __shfl_down(a3, off, 8);
        a4 += __shfl_down(a4, off, 8);
        a5 += __shfl_down(a5, off, 8);
    }
    if (s == 0) {
        simg[b][0] = a0;
        simg[b][1] = a1;
        simg[b][2] = a2;
        simg[b][3] = 2.0f * a3 / (a4 + a5 + 1e-8f);   // dice_b
    }
    __syncthreads();
    if (t < BATCH) {
        float ce  = simg[t][0];
        float cnt = simg[t][1];
        float foc = simg[t][2];
        float dc  = simg[t][3];
        #pragma unroll
        for (int off = 16; off > 0; off >>= 1) {
            ce  += __shfl_down(ce,  off, 32);
            cnt += __shfl_down(cnt, off, 32);
            foc += __shfl_down(foc, off, 32);
            dc  += __shfl_down(dc,  off, 32);
        }
        if (t == 0) {
            const float ce_loss = ce / fmaxf(cnt, 1.0f);
            const float focal   = foc / NPIX;
            const float bdice   = 1.0f - dc / (float)BATCH;
            out[0] = ce_loss + focal + bdice;   // BOUNDARY_W = 1.0
        }
    }
}

extern "C" void kernel_launch(void* const* d_in, const int* in_sizes, int n_in,
                              void* d_out, int out_size, void* d_ws, size_t ws_size,
                              hipStream_t stream) {
    const float* pred   = (const float*)d_in[0];
    const int*   target = (const int*)d_in[1];
    float* ws  = (float*)d_ws;
    float* out = (float*)d_out;

    bel_main_kernel<<<NBLK, 256, 0, stream>>>(pred, target, ws);
    bel_finalize_kernel<<<1, 256, 0, stream>>>(ws, out);
}